// Round 2
// baseline (200.782 us; speedup 1.0000x reference)
//
#include <hip/hip_runtime.h>

#define IMG 224
#define HW (IMG * IMG)
#define TILE 32

__global__ __launch_bounds__(256, 5) void vm_kernel(
    const float* __restrict__ im1, const float* __restrict__ im2,
    const float* __restrict__ C, const float* __restrict__ M1,
    const float* __restrict__ M2, float* __restrict__ out)
{
    // +1 padding -> conflict-free in both access orders
    __shared__ float sC0[TILE][TILE + 1];
    __shared__ float sC1[TILE][TILE + 1];
    __shared__ float sM1[TILE][TILE + 1];
    __shared__ float sM2[TILE][TILE + 1];
    __shared__ float sO[3][TILE][TILE + 1];

    const int n    = blockIdx.y;
    const int tile = blockIdx.x;          // 0..48
    const int x0   = (tile / 7) * TILE;   // slow output dim (p / 224)
    const int y0   = (tile % 7) * TILE;   // fast output dim (p % 224)
    const int t    = threadIdx.x;

    const float* Cn  = C  + (size_t)n * 2 * HW;
    const float* M1n = M1 + (size_t)n * HW;
    const float* M2n = M2 + (size_t)n * HW;

    // ---- phase 1: coalesced tile load of C0, C1, M1, M2 (output-layout order)
#pragma unroll
    for (int j = 0; j < 4; ++j) {
        int idx = t + 256 * j;            // 0..1023
        int tx  = idx >> 5;               // x offset in tile
        int ty  = idx & 31;               // y offset (fast in memory)
        int p   = (x0 + tx) * IMG + (y0 + ty);
        sC0[tx][ty] = Cn[p];
        sC1[tx][ty] = Cn[HW + p];
        sM1[tx][ty] = M1n[p];
        sM2[tx][ty] = M2n[p];
    }
    __syncthreads();

    const float* i1n = im1 + (size_t)n * 3 * HW;
    const float* i2n = im2 + (size_t)n * 3 * HW;

    // ---- phase 2: compute in TRANSPOSED order (x fast) so gathers coalesce.
    // All 24 gathers of a pixel are issued into result arrays BEFORE any use,
    // so the compiler can keep them all in flight (MLP), instead of 8-load
    // batches serialized by vmcnt drains.
#pragma unroll
    for (int j = 0; j < 4; ++j) {
        int idx = t + 256 * j;
        int xl  = idx & 31;               // x fast across lanes
        int yl  = idx >> 5;
        float c0 = sC0[xl][yl];
        float c1 = sC1[xl][yl];
        float m1 = sM1[xl][yl];
        float m2 = sM2[xl][yl];
        float xf = (float)(x0 + xl);
        float yf = (float)(y0 + yl);

        int   ia[4], ib[4];
        float wa[4], wb[4];

        // --- direction +C on im1
        {
            float px = xf + c0, py = yf + c1;
            float fx = floorf(px), cx = ceilf(px);
            float fy = floorf(py), cy = ceilf(py);
            float wfx = 1.0f - (px - fx), wcx = 1.0f - (cx - px);
            float wfy = 1.0f - (py - fy), wcy = 1.0f - (cy - py);
            ia[0] = min(max((int)fx + IMG * (int)fy, 0), HW - 1);
            ia[1] = min(max((int)cx + IMG * (int)fy, 0), HW - 1);
            ia[2] = min(max((int)fx + IMG * (int)cy, 0), HW - 1);
            ia[3] = min(max((int)cx + IMG * (int)cy, 0), HW - 1);
            wa[0] = wfx * wfy; wa[1] = wcx * wfy;
            wa[2] = wfx * wcy; wa[3] = wcx * wcy;
        }
        // --- direction -C on im2
        {
            float px = xf - c0, py = yf - c1;
            float fx = floorf(px), cx = ceilf(px);
            float fy = floorf(py), cy = ceilf(py);
            float wfx = 1.0f - (px - fx), wcx = 1.0f - (cx - px);
            float wfy = 1.0f - (py - fy), wcy = 1.0f - (cy - py);
            ib[0] = min(max((int)fx + IMG * (int)fy, 0), HW - 1);
            ib[1] = min(max((int)cx + IMG * (int)fy, 0), HW - 1);
            ib[2] = min(max((int)fx + IMG * (int)cy, 0), HW - 1);
            ib[3] = min(max((int)cx + IMG * (int)cy, 0), HW - 1);
            wb[0] = wfx * wfy; wb[1] = wcx * wfy;
            wb[2] = wfx * wcy; wb[3] = wcx * wcy;
        }

        // --- issue all 24 gathers before any use
        float ra[12], rb[12];
#pragma unroll
        for (int ch = 0; ch < 3; ++ch) {
            const float* pa = i1n + ch * HW;
#pragma unroll
            for (int k = 0; k < 4; ++k) ra[ch * 4 + k] = pa[ia[k]];
        }
#pragma unroll
        for (int ch = 0; ch < 3; ++ch) {
            const float* pb = i2n + ch * HW;
#pragma unroll
            for (int k = 0; k < 4; ++k) rb[ch * 4 + k] = pb[ib[k]];
        }

        // --- accumulate
#pragma unroll
        for (int ch = 0; ch < 3; ++ch) {
            float a = wa[0] * ra[ch * 4 + 0] + wa[1] * ra[ch * 4 + 1]
                    + wa[2] * ra[ch * 4 + 2] + wa[3] * ra[ch * 4 + 3];
            float b = wb[0] * rb[ch * 4 + 0] + wb[1] * rb[ch * 4 + 1]
                    + wb[2] * rb[ch * 4 + 2] + wb[3] * rb[ch * 4 + 3];
            sO[ch][xl][yl] = a * m1 + b * m2;
        }
    }
    __syncthreads();

    // ---- phase 3: coalesced store in output-layout order
    float* on = out + (size_t)n * 3 * HW;
#pragma unroll
    for (int j = 0; j < 4; ++j) {
        int idx = t + 256 * j;
        int tx  = idx >> 5;
        int ty  = idx & 31;
        int p   = (x0 + tx) * IMG + (y0 + ty);
#pragma unroll
        for (int ch = 0; ch < 3; ++ch) {
            on[ch * HW + p] = sO[ch][tx][ty];
        }
    }
}

extern "C" void kernel_launch(void* const* d_in, const int* in_sizes, int n_in,
                              void* d_out, int out_size, void* d_ws, size_t ws_size,
                              hipStream_t stream) {
    const float* im1 = (const float*)d_in[0];
    const float* im2 = (const float*)d_in[1];
    const float* C   = (const float*)d_in[2];
    const float* M1  = (const float*)d_in[3];
    const float* M2  = (const float*)d_in[4];
    float* out = (float*)d_out;
    dim3 grid(49, 64);  // 7x7 tiles of 32x32, 64 batch
    vm_kernel<<<grid, 256, 0, stream>>>(im1, im2, C, M1, M2, out);
}

// Round 3
// 196.611 us; speedup vs baseline: 1.0212x; 1.0212x over previous
//
#include <hip/hip_runtime.h>

#define IMG 224
#define HW (IMG * IMG)
#define TILE 32
#define PAD 5
#define REG (TILE + 2 * PAD)       // 42: staged rows/cols per tile
#define RST (REG + 1)              // 43: LDS stride (non-pow2 -> bank spread)
#define UT (TILE * (TILE + 1))     // 1056 floats per transpose tile

__global__ __launch_bounds__(256, 4) void vm_kernel(
    const float* __restrict__ im1, const float* __restrict__ im2,
    const float* __restrict__ C, const float* __restrict__ M1,
    const float* __restrict__ M2, float* __restrict__ out)
{
    // uni: phase0 holds C0,C1,M1,M2 transpose tiles; after that reused as sO[3]
    __shared__ float uni[4 * UT];          // 16896 B
    __shared__ float sA[REG * RST];        // 7224 B  (im1 channel tile, flat-clamp staged)
    __shared__ float sB[REG * RST];        // 7224 B  (im2 channel tile)

    const int n    = blockIdx.y;
    const int tile = blockIdx.x;           // 0..48
    const int x0   = (tile / 7) * TILE;    // slow output coord (p / 224) == gather col nx
    const int y0   = (tile % 7) * TILE;    // fast output coord (p % 224) == gather row ny
    const int t    = threadIdx.x;
    const int xlo  = x0 - PAD;
    const int ylo  = y0 - PAD;

    const float* Cn  = C  + (size_t)n * 2 * HW;
    const float* M1n = M1 + (size_t)n * HW;
    const float* M2n = M2 + (size_t)n * HW;

    // ---- phase 0: coalesced load of C0,C1,M1,M2 + LDS transpose into registers
#pragma unroll
    for (int j = 0; j < 4; ++j) {
        int idx = t + 256 * j;
        int tx  = idx >> 5;
        int ty  = idx & 31;
        int p   = (x0 + tx) * IMG + (y0 + ty);
        uni[0 * UT + tx * 33 + ty] = Cn[p];
        uni[1 * UT + tx * 33 + ty] = Cn[HW + p];
        uni[2 * UT + tx * 33 + ty] = M1n[p];
        uni[3 * UT + tx * 33 + ty] = M2n[p];
    }
    __syncthreads();
    float c0[4], c1[4], m1v[4], m2v[4];
#pragma unroll
    for (int j = 0; j < 4; ++j) {
        int idx = t + 256 * j;
        int xl  = idx & 31;
        int yl  = idx >> 5;
        c0[j]  = uni[0 * UT + xl * 33 + yl];
        c1[j]  = uni[1 * UT + xl * 33 + yl];
        m1v[j] = uni[2 * UT + xl * 33 + yl];
        m2v[j] = uni[3 * UT + xl * 33 + yl];
    }
    __syncthreads();

    // ---- precompute: per pixel, per direction: 4 LDS offsets, 4 weights,
    //      wave-uniform fast flag (all corners inside staged region)
    int   offA[4][4], offB[4][4];
    float wA[4][4],   wB[4][4];
    int   fa[4], fb[4];
#pragma unroll
    for (int j = 0; j < 4; ++j) {
        int idx = t + 256 * j;
        int xl  = idx & 31;
        int yl  = idx >> 5;
        float xf = (float)(x0 + xl);
        float yf = (float)(y0 + yl);
        {   // +C on im1
            float px = xf + c0[j], py = yf + c1[j];
            float fx = floorf(px), cx = ceilf(px);
            float fy = floorf(py), cy = ceilf(py);
            float wfx = 1.0f - (px - fx), wcx = 1.0f - (cx - px);
            float wfy = 1.0f - (py - fy), wcy = 1.0f - (cy - py);
            wA[j][0] = wfx * wfy; wA[j][1] = wcx * wfy;
            wA[j][2] = wfx * wcy; wA[j][3] = wcx * wcy;
            int gx0 = (int)fx, gy0 = (int)fy;
            int dx  = (int)cx - gx0, dy = (int)cy - gy0;
            int q0  = gx0 - xlo, r0 = gy0 - ylo;
            int o   = r0 * RST + q0;
            offA[j][0] = o;            offA[j][1] = o + dx;
            offA[j][2] = o + dy * RST; offA[j][3] = o + dx + dy * RST;
            int f = (q0 >= 0) & (q0 + dx <= REG - 1) & (r0 >= 0) & (r0 + dy <= REG - 1);
            fa[j] = __all(f);
        }
        {   // -C on im2
            float px = xf - c0[j], py = yf - c1[j];
            float fx = floorf(px), cx = ceilf(px);
            float fy = floorf(py), cy = ceilf(py);
            float wfx = 1.0f - (px - fx), wcx = 1.0f - (cx - px);
            float wfy = 1.0f - (py - fy), wcy = 1.0f - (cy - py);
            wB[j][0] = wfx * wfy; wB[j][1] = wcx * wfy;
            wB[j][2] = wfx * wcy; wB[j][3] = wcx * wcy;
            int gx0 = (int)fx, gy0 = (int)fy;
            int dx  = (int)cx - gx0, dy = (int)cy - gy0;
            int q0  = gx0 - xlo, r0 = gy0 - ylo;
            int o   = r0 * RST + q0;
            offB[j][0] = o;            offB[j][1] = o + dx;
            offB[j][2] = o + dy * RST; offB[j][3] = o + dx + dy * RST;
            int f = (q0 >= 0) & (q0 + dx <= REG - 1) & (r0 >= 0) & (r0 + dy <= REG - 1);
            fb[j] = __all(f);
        }
    }

    const float* i1n = im1 + (size_t)n * 3 * HW;
    const float* i2n = im2 + (size_t)n * 3 * HW;

    // ---- channel loop: stage flat-clamped halo tiles, gather from LDS
#pragma unroll
    for (int ch = 0; ch < 3; ++ch) {
        __syncthreads();   // protect prior-iter tile reads / phase-0 uni reads
        const float* pa = i1n + ch * HW;
        const float* pb = i2n + ch * HW;
        for (int e = t; e < REG * REG; e += 256) {
            int r  = e / REG;
            int c  = e - r * REG;
            int gi = (xlo + c) + IMG * (ylo + r);      // flat index, reference clamp
            gi = min(max(gi, 0), HW - 1);
            sA[r * RST + c] = pa[gi];
            sB[r * RST + c] = pb[gi];
        }
        __syncthreads();
#pragma unroll
        for (int j = 0; j < 4; ++j) {
            int idx = t + 256 * j;
            int xl  = idx & 31;
            int yl  = idx >> 5;
            float a, b;
            if (fa[j]) {
                a = wA[j][0] * sA[offA[j][0]] + wA[j][1] * sA[offA[j][1]]
                  + wA[j][2] * sA[offA[j][2]] + wA[j][3] * sA[offA[j][3]];
            } else {  // rare: displacement beyond PAD -> global clamped gather
                float px = (float)(x0 + xl) + c0[j], py = (float)(y0 + yl) + c1[j];
                float fx = floorf(px), cx = ceilf(px);
                float fy = floorf(py), cy = ceilf(py);
                int i0 = min(max((int)fx + IMG * (int)fy, 0), HW - 1);
                int i1 = min(max((int)cx + IMG * (int)fy, 0), HW - 1);
                int i2 = min(max((int)fx + IMG * (int)cy, 0), HW - 1);
                int i3 = min(max((int)cx + IMG * (int)cy, 0), HW - 1);
                a = wA[j][0] * pa[i0] + wA[j][1] * pa[i1]
                  + wA[j][2] * pa[i2] + wA[j][3] * pa[i3];
            }
            if (fb[j]) {
                b = wB[j][0] * sB[offB[j][0]] + wB[j][1] * sB[offB[j][1]]
                  + wB[j][2] * sB[offB[j][2]] + wB[j][3] * sB[offB[j][3]];
            } else {
                float px = (float)(x0 + xl) - c0[j], py = (float)(y0 + yl) - c1[j];
                float fx = floorf(px), cx = ceilf(px);
                float fy = floorf(py), cy = ceilf(py);
                int i0 = min(max((int)fx + IMG * (int)fy, 0), HW - 1);
                int i1 = min(max((int)cx + IMG * (int)fy, 0), HW - 1);
                int i2 = min(max((int)fx + IMG * (int)cy, 0), HW - 1);
                int i3 = min(max((int)cx + IMG * (int)cy, 0), HW - 1);
                b = wB[j][0] * pb[i0] + wB[j][1] * pb[i1]
                  + wB[j][2] * pb[i2] + wB[j][3] * pb[i3];
            }
            uni[ch * UT + xl * 33 + yl] = a * m1v[j] + b * m2v[j];
        }
    }
    __syncthreads();

    // ---- phase 3: coalesced store in output-layout order
    float* on = out + (size_t)n * 3 * HW;
#pragma unroll
    for (int j = 0; j < 4; ++j) {
        int idx = t + 256 * j;
        int tx  = idx >> 5;
        int ty  = idx & 31;
        int p   = (x0 + tx) * IMG + (y0 + ty);
#pragma unroll
        for (int ch = 0; ch < 3; ++ch) {
            on[ch * HW + p] = uni[ch * UT + tx * 33 + ty];
        }
    }
}

extern "C" void kernel_launch(void* const* d_in, const int* in_sizes, int n_in,
                              void* d_out, int out_size, void* d_ws, size_t ws_size,
                              hipStream_t stream) {
    const float* im1 = (const float*)d_in[0];
    const float* im2 = (const float*)d_in[1];
    const float* C   = (const float*)d_in[2];
    const float* M1  = (const float*)d_in[3];
    const float* M2  = (const float*)d_in[4];
    float* out = (float*)d_out;
    dim3 grid(49, 64);  // 7x7 tiles of 32x32, 64 batch
    vm_kernel<<<grid, 256, 0, stream>>>(im1, im2, C, M1, M2, out);
}

// Round 4
// 181.844 us; speedup vs baseline: 1.1041x; 1.0812x over previous
//
#include <hip/hip_runtime.h>

#define IMG 224
#define HW (IMG * IMG)
#define TILE 32
#define PAD 4
#define REG (TILE + 2 * PAD)       // 40: staged rows/cols per tile
#define RST (REG + 1)              // 41: LDS row stride
#define TSZ (REG * RST)            // 1640 floats per staged image tile
#define UT  (TILE * (TILE + 1))    // 1056 floats per transpose tile

__global__ __launch_bounds__(256, 4) void vm_kernel(
    const float* __restrict__ im1, const float* __restrict__ im2,
    const float* __restrict__ C, const float* __restrict__ M1,
    const float* __restrict__ M2, float* __restrict__ out)
{
    // Single LDS arena, reused three times:
    //  phase 0: first 4*UT floats = C0,C1,M1,M2 transpose tiles
    //  phase 1: 6 staged image tiles (im1 ch0..2, im2 ch0..2), flat-clamp semantics
    //  phase 3: first 3*UT floats = output transpose tiles
    __shared__ float smem[6 * TSZ];        // 39360 B -> 4 blocks/CU

    const int n    = blockIdx.y;
    const int tile = blockIdx.x;           // 0..48
    const int x0   = (tile / 7) * TILE;    // gather col coord (p / 224)
    const int y0   = (tile % 7) * TILE;    // gather row coord (p % 224)
    const int t    = threadIdx.x;
    const int xlo  = x0 - PAD;
    const int ylo  = y0 - PAD;

    const float* Cn  = C  + (size_t)n * 2 * HW;
    const float* M1n = M1 + (size_t)n * HW;
    const float* M2n = M2 + (size_t)n * HW;

    // ---- phase 0: coalesced load of C0,C1,M1,M2 + LDS transpose to registers
#pragma unroll
    for (int j = 0; j < 4; ++j) {
        int idx = t + 256 * j;
        int tx  = idx >> 5;
        int ty  = idx & 31;
        int p   = (x0 + tx) * IMG + (y0 + ty);
        smem[0 * UT + tx * 33 + ty] = Cn[p];
        smem[1 * UT + tx * 33 + ty] = Cn[HW + p];
        smem[2 * UT + tx * 33 + ty] = M1n[p];
        smem[3 * UT + tx * 33 + ty] = M2n[p];
    }
    __syncthreads();
    float c0[4], c1[4], m1v[4], m2v[4];
#pragma unroll
    for (int j = 0; j < 4; ++j) {
        int idx = t + 256 * j;
        int xl  = idx & 31;
        int yl  = idx >> 5;
        c0[j]  = smem[0 * UT + xl * 33 + yl];
        c1[j]  = smem[1 * UT + xl * 33 + yl];
        m1v[j] = smem[2 * UT + xl * 33 + yl];
        m2v[j] = smem[3 * UT + xl * 33 + yl];
    }
    __syncthreads();

    // ---- phase 1: stage ALL 6 channel tiles (im1 x3, im2 x3) with the
    //      reference's flat-index clamp baked in. 42 batched global loads.
    const float* i1n = im1 + (size_t)n * 3 * HW;
    const float* i2n = im2 + (size_t)n * 3 * HW;
    for (int e = t; e < REG * REG; e += 256) {
        int r  = e / REG;
        int c  = e - r * REG;
        int gi = (xlo + c) + IMG * (ylo + r);
        gi = min(max(gi, 0), HW - 1);
        int ls = r * RST + c;
#pragma unroll
        for (int ch = 0; ch < 3; ++ch) {
            smem[ch * TSZ + ls]       = i1n[ch * HW + gi];
            smem[(3 + ch) * TSZ + ls] = i2n[ch * HW + gi];
        }
    }
    __syncthreads();

    // ---- phase 2: per pixel: 8 offsets + 8 weights (registers, short-lived),
    //      24 LDS gathers, accumulate into res[12]. No large live arrays.
    float res[12];
#pragma unroll
    for (int j = 0; j < 4; ++j) {
        int idx = t + 256 * j;
        int xl  = idx & 31;
        int yl  = idx >> 5;
        float xf = (float)(x0 + xl);
        float yf = (float)(y0 + yl);

        int   oA[4], oB[4];
        float wA[4], wB[4];
        int fa, fb;
        {   // +C on im1
            float px = xf + c0[j], py = yf + c1[j];
            float fx = floorf(px), cx = ceilf(px);
            float fy = floorf(py), cy = ceilf(py);
            float wfx = 1.0f - (px - fx), wcx = 1.0f - (cx - px);
            float wfy = 1.0f - (py - fy), wcy = 1.0f - (cy - py);
            wA[0] = wfx * wfy; wA[1] = wcx * wfy;
            wA[2] = wfx * wcy; wA[3] = wcx * wcy;
            int gx0 = (int)fx, gy0 = (int)fy;
            int dx = (int)cx - gx0, dy = (int)cy - gy0;
            int q0 = gx0 - xlo, r0 = gy0 - ylo;
            int o  = r0 * RST + q0;
            oA[0] = o;            oA[1] = o + dx;
            oA[2] = o + dy * RST; oA[3] = o + dx + dy * RST;
            fa = __all((q0 >= 0) & (q0 + dx <= REG - 1) &
                       (r0 >= 0) & (r0 + dy <= REG - 1));
        }
        {   // -C on im2
            float px = xf - c0[j], py = yf - c1[j];
            float fx = floorf(px), cx = ceilf(px);
            float fy = floorf(py), cy = ceilf(py);
            float wfx = 1.0f - (px - fx), wcx = 1.0f - (cx - px);
            float wfy = 1.0f - (py - fy), wcy = 1.0f - (cy - py);
            wB[0] = wfx * wfy; wB[1] = wcx * wfy;
            wB[2] = wfx * wcy; wB[3] = wcx * wcy;
            int gx0 = (int)fx, gy0 = (int)fy;
            int dx = (int)cx - gx0, dy = (int)cy - gy0;
            int q0 = gx0 - xlo, r0 = gy0 - ylo;
            int o  = r0 * RST + q0;
            oB[0] = o;            oB[1] = o + dx;
            oB[2] = o + dy * RST; oB[3] = o + dx + dy * RST;
            fb = __all((q0 >= 0) & (q0 + dx <= REG - 1) &
                       (r0 >= 0) & (r0 + dy <= REG - 1));
        }

        if (fa) {
#pragma unroll
            for (int ch = 0; ch < 3; ++ch) {
                const float* T = smem + ch * TSZ;
                res[j * 3 + ch] = m1v[j] *
                    (wA[0] * T[oA[0]] + wA[1] * T[oA[1]] +
                     wA[2] * T[oA[2]] + wA[3] * T[oA[3]]);
            }
        } else {  // rare (<1% of wave-groups): global clamped gather
            float px = xf + c0[j], py = yf + c1[j];
            float fx = floorf(px), cx = ceilf(px);
            float fy = floorf(py), cy = ceilf(py);
            int i0 = min(max((int)fx + IMG * (int)fy, 0), HW - 1);
            int i1 = min(max((int)cx + IMG * (int)fy, 0), HW - 1);
            int i2 = min(max((int)fx + IMG * (int)cy, 0), HW - 1);
            int i3 = min(max((int)cx + IMG * (int)cy, 0), HW - 1);
#pragma unroll
            for (int ch = 0; ch < 3; ++ch) {
                const float* pa = i1n + ch * HW;
                res[j * 3 + ch] = m1v[j] *
                    (wA[0] * pa[i0] + wA[1] * pa[i1] +
                     wA[2] * pa[i2] + wA[3] * pa[i3]);
            }
        }
        if (fb) {
#pragma unroll
            for (int ch = 0; ch < 3; ++ch) {
                const float* T = smem + (3 + ch) * TSZ;
                res[j * 3 + ch] += m2v[j] *
                    (wB[0] * T[oB[0]] + wB[1] * T[oB[1]] +
                     wB[2] * T[oB[2]] + wB[3] * T[oB[3]]);
            }
        } else {
            float px = xf - c0[j], py = yf - c1[j];
            float fx = floorf(px), cx = ceilf(px);
            float fy = floorf(py), cy = ceilf(py);
            int i0 = min(max((int)fx + IMG * (int)fy, 0), HW - 1);
            int i1 = min(max((int)cx + IMG * (int)fy, 0), HW - 1);
            int i2 = min(max((int)fx + IMG * (int)cy, 0), HW - 1);
            int i3 = min(max((int)cx + IMG * (int)cy, 0), HW - 1);
#pragma unroll
            for (int ch = 0; ch < 3; ++ch) {
                const float* pb = i2n + ch * HW;
                res[j * 3 + ch] += m2v[j] *
                    (wB[0] * pb[i0] + wB[1] * pb[i1] +
                     wB[2] * pb[i2] + wB[3] * pb[i3]);
            }
        }
    }
    __syncthreads();   // all gathers done -> safe to reuse smem

    // ---- phase 3: transpose results through LDS, coalesced store
#pragma unroll
    for (int j = 0; j < 4; ++j) {
        int idx = t + 256 * j;
        int xl  = idx & 31;
        int yl  = idx >> 5;
#pragma unroll
        for (int ch = 0; ch < 3; ++ch)
            smem[ch * UT + xl * 33 + yl] = res[j * 3 + ch];
    }
    __syncthreads();
    float* on = out + (size_t)n * 3 * HW;
#pragma unroll
    for (int j = 0; j < 4; ++j) {
        int idx = t + 256 * j;
        int tx  = idx >> 5;
        int ty  = idx & 31;
        int p   = (x0 + tx) * IMG + (y0 + ty);
#pragma unroll
        for (int ch = 0; ch < 3; ++ch)
            on[ch * HW + p] = smem[ch * UT + tx * 33 + ty];
    }
}

extern "C" void kernel_launch(void* const* d_in, const int* in_sizes, int n_in,
                              void* d_out, int out_size, void* d_ws, size_t ws_size,
                              hipStream_t stream) {
    const float* im1 = (const float*)d_in[0];
    const float* im2 = (const float*)d_in[1];
    const float* C   = (const float*)d_in[2];
    const float* M1  = (const float*)d_in[3];
    const float* M2  = (const float*)d_in[4];
    float* out = (float*)d_out;
    dim3 grid(49, 64);  // 7x7 tiles of 32x32, 64 batch
    vm_kernel<<<grid, 256, 0, stream>>>(im1, im2, C, M1, M2, out);
}

// Round 5
// 172.963 us; speedup vs baseline: 1.1608x; 1.0514x over previous
//
#include <hip/hip_runtime.h>

#define IMG 224
#define HW (IMG * IMG)
#define TILE 32
#define PAD 4
#define REG (TILE + 2 * PAD)       // 40: staged rows/cols per tile
#define RST (REG + 1)              // 41: LDS row stride (odd -> stride-41 lane
                                   //     access is a full bank permutation)
#define TSZ (REG * RST)            // 1640 floats per staged image tile

__global__ __launch_bounds__(256, 4) void vm_kernel(
    const float* __restrict__ im1, const float* __restrict__ im2,
    const float* __restrict__ C, const float* __restrict__ M1,
    const float* __restrict__ M2, float* __restrict__ out)
{
    // LDS holds ONLY the 6 staged image tiles (im1 ch0..2, im2 ch0..2),
    // flat-index-clamp semantics baked in at staging time.
    __shared__ float smem[6 * TSZ];        // 39360 B -> 4 blocks/CU

    const int n    = blockIdx.y;
    const int tile = blockIdx.x;           // 0..48
    const int x0   = (tile / 7) * TILE;    // gather col coord (p / 224)
    const int y0   = (tile % 7) * TILE;    // gather row coord (p % 224)
    const int t    = threadIdx.x;
    const int xlo  = x0 - PAD;
    const int ylo  = y0 - PAD;

    const float* i1n = im1 + (size_t)n * 3 * HW;
    const float* i2n = im2 + (size_t)n * 3 * HW;
    const float* Cn  = C  + (size_t)n * 2 * HW;
    const float* M1n = M1 + (size_t)n * HW;
    const float* M2n = M2 + (size_t)n * HW;

    // ---- phase 1: stage all 6 channel tiles. 42 independent global loads
    //      per thread, all issued before the single barrier.
#pragma unroll
    for (int k = 0; k < 7; ++k) {
        int e = t + 256 * k;
        if (e < REG * REG) {               // only k=6 is partial (wave-uniform)
            int r  = e / REG;
            int c  = e - r * REG;
            int gi = (xlo + c) + IMG * (ylo + r);   // reference flat clamp
            gi = min(max(gi, 0), HW - 1);
            int ls = r * RST + c;
#pragma unroll
            for (int ch = 0; ch < 3; ++ch) {
                smem[ch * TSZ + ls]       = i1n[ch * HW + gi];
                smem[(3 + ch) * TSZ + ls] = i2n[ch * HW + gi];
            }
        }
    }

    // ---- C/M straight to registers, natural (y-fast) order -> coalesced.
    float c0[4], c1[4], m1v[4], m2v[4];
#pragma unroll
    for (int j = 0; j < 4; ++j) {
        int idx = t + 256 * j;
        int tx  = idx >> 5;                // slow coord (p / 224)
        int ty  = idx & 31;                // fast coord (p % 224)
        int p   = (x0 + tx) * IMG + (y0 + ty);
        c0[j]  = Cn[p];
        c1[j]  = Cn[HW + p];
        m1v[j] = M1n[p];
        m2v[j] = M2n[p];
    }

    __syncthreads();                       // the ONLY barrier

    // ---- phase 2: per pixel compute, LDS gathers, direct coalesced store.
    float* on = out + (size_t)n * 3 * HW;
#pragma unroll
    for (int j = 0; j < 4; ++j) {
        int idx = t + 256 * j;
        int tx  = idx >> 5;
        int ty  = idx & 31;
        int p   = (x0 + tx) * IMG + (y0 + ty);
        float xf = (float)(x0 + tx);
        float yf = (float)(y0 + ty);

        int   oA[4], oB[4];
        float wA[4], wB[4];
        int fa, fb;
        {   // +C on im1
            float px = xf + c0[j], py = yf + c1[j];
            float fx = floorf(px), cx = ceilf(px);
            float fy = floorf(py), cy = ceilf(py);
            float wfx = 1.0f - (px - fx), wcx = 1.0f - (cx - px);
            float wfy = 1.0f - (py - fy), wcy = 1.0f - (cy - py);
            wA[0] = wfx * wfy; wA[1] = wcx * wfy;
            wA[2] = wfx * wcy; wA[3] = wcx * wcy;
            int gx0 = (int)fx, gy0 = (int)fy;
            int dx = (int)cx - gx0, dy = (int)cy - gy0;
            int q0 = gx0 - xlo, r0 = gy0 - ylo;
            int o  = r0 * RST + q0;
            oA[0] = o;            oA[1] = o + dx;
            oA[2] = o + dy * RST; oA[3] = o + dx + dy * RST;
            fa = __all((q0 >= 0) & (q0 + dx <= REG - 1) &
                       (r0 >= 0) & (r0 + dy <= REG - 1));
        }
        {   // -C on im2
            float px = xf - c0[j], py = yf - c1[j];
            float fx = floorf(px), cx = ceilf(px);
            float fy = floorf(py), cy = ceilf(py);
            float wfx = 1.0f - (px - fx), wcx = 1.0f - (cx - px);
            float wfy = 1.0f - (py - fy), wcy = 1.0f - (cy - py);
            wB[0] = wfx * wfy; wB[1] = wcx * wfy;
            wB[2] = wfx * wcy; wB[3] = wcx * wcy;
            int gx0 = (int)fx, gy0 = (int)fy;
            int dx = (int)cx - gx0, dy = (int)cy - gy0;
            int q0 = gx0 - xlo, r0 = gy0 - ylo;
            int o  = r0 * RST + q0;
            oB[0] = o;            oB[1] = o + dx;
            oB[2] = o + dy * RST; oB[3] = o + dx + dy * RST;
            fb = __all((q0 >= 0) & (q0 + dx <= REG - 1) &
                       (r0 >= 0) & (r0 + dy <= REG - 1));
        }

        float res[3];
        if (fa) {
#pragma unroll
            for (int ch = 0; ch < 3; ++ch) {
                const float* T = smem + ch * TSZ;
                res[ch] = m1v[j] *
                    (wA[0] * T[oA[0]] + wA[1] * T[oA[1]] +
                     wA[2] * T[oA[2]] + wA[3] * T[oA[3]]);
            }
        } else {  // rare: displacement beyond PAD -> global clamped gather
            float px = xf + c0[j], py = yf + c1[j];
            float fx = floorf(px), cx = ceilf(px);
            float fy = floorf(py), cy = ceilf(py);
            int i0 = min(max((int)fx + IMG * (int)fy, 0), HW - 1);
            int i1 = min(max((int)cx + IMG * (int)fy, 0), HW - 1);
            int i2 = min(max((int)fx + IMG * (int)cy, 0), HW - 1);
            int i3 = min(max((int)cx + IMG * (int)cy, 0), HW - 1);
#pragma unroll
            for (int ch = 0; ch < 3; ++ch) {
                const float* pa = i1n + ch * HW;
                res[ch] = m1v[j] *
                    (wA[0] * pa[i0] + wA[1] * pa[i1] +
                     wA[2] * pa[i2] + wA[3] * pa[i3]);
            }
        }
        if (fb) {
#pragma unroll
            for (int ch = 0; ch < 3; ++ch) {
                const float* T = smem + (3 + ch) * TSZ;
                res[ch] += m2v[j] *
                    (wB[0] * T[oB[0]] + wB[1] * T[oB[1]] +
                     wB[2] * T[oB[2]] + wB[3] * T[oB[3]]);
            }
        } else {
            float px = xf - c0[j], py = yf - c1[j];
            float fx = floorf(px), cx = ceilf(px);
            float fy = floorf(py), cy = ceilf(py);
            int i0 = min(max((int)fx + IMG * (int)fy, 0), HW - 1);
            int i1 = min(max((int)cx + IMG * (int)fy, 0), HW - 1);
            int i2 = min(max((int)fx + IMG * (int)cy, 0), HW - 1);
            int i3 = min(max((int)cx + IMG * (int)cy, 0), HW - 1);
#pragma unroll
            for (int ch = 0; ch < 3; ++ch) {
                const float* pb = i2n + ch * HW;
                res[ch] += m2v[j] *
                    (wB[0] * pb[i0] + wB[1] * pb[i1] +
                     wB[2] * pb[i2] + wB[3] * pb[i3]);
            }
        }

        // direct coalesced store (lanes consecutive in ty -> contiguous)
#pragma unroll
        for (int ch = 0; ch < 3; ++ch)
            on[ch * HW + p] = res[ch];
    }
}

extern "C" void kernel_launch(void* const* d_in, const int* in_sizes, int n_in,
                              void* d_out, int out_size, void* d_ws, size_t ws_size,
                              hipStream_t stream) {
    const float* im1 = (const float*)d_in[0];
    const float* im2 = (const float*)d_in[1];
    const float* C   = (const float*)d_in[2];
    const float* M1  = (const float*)d_in[3];
    const float* M2  = (const float*)d_in[4];
    float* out = (float*)d_out;
    dim3 grid(49, 64);  // 7x7 tiles of 32x32, 64 batch
    vm_kernel<<<grid, 256, 0, stream>>>(im1, im2, C, M1, M2, out);
}